// Round 1
// baseline (63.388 us; speedup 1.0000x reference)
//
#include <hip/hip_runtime.h>

#define BLOCK 256
#define FPT 12   // floats per thread = 4 triples = 3 float4

__global__ __launch_bounds__(BLOCK)
void rot3_kernel(const float* __restrict__ x, const float* __restrict__ theta,
                 float* __restrict__ out, int blocks_per_b, long total_floats) {
    __shared__ float Rs[9];
    const int b = blockIdx.x / blocks_per_b;
    if (threadIdx.x == 0) {
        // Indexing per reference: Rx uses th[1], Ry uses th[0], Rz uses th[2]
        const float t0 = theta[3 * b + 0];
        const float t1 = theta[3 * b + 1];
        const float t2 = theta[3 * b + 2];
        float sx, cx, sy, cy, sz, cz;
        sincosf(t1, &sx, &cx);
        sincosf(t0, &sy, &cy);
        sincosf(t2, &sz, &cz);
        // R = Rz * Ry * Rx (3x3 block; homogeneous part is identity)
        Rs[0] = cz * cy;
        Rs[1] = cz * sy * sx - sz * cx;
        Rs[2] = sz * sx + cz * sy * cx;
        Rs[3] = sz * cy;
        Rs[4] = cz * cx + sz * sy * sx;
        Rs[5] = sz * sy * cx - cz * sx;
        Rs[6] = -sy;
        Rs[7] = cy * sx;
        Rs[8] = cy * cx;
    }
    __syncthreads();
    const float r00 = Rs[0], r01 = Rs[1], r02 = Rs[2];
    const float r10 = Rs[3], r11 = Rs[4], r12 = Rs[5];
    const float r20 = Rs[6], r21 = Rs[7], r22 = Rs[8];

    const long base = ((long)blockIdx.x * BLOCK + threadIdx.x) * (long)FPT;
    if (base + FPT > total_floats) return;

    const float4* __restrict__ xin = reinterpret_cast<const float4*>(x + base);
    const float4 v0 = xin[0];
    const float4 v1 = xin[1];
    const float4 v2 = xin[2];

    const float p[12] = {v0.x, v0.y, v0.z, v0.w,
                         v1.x, v1.y, v1.z, v1.w,
                         v2.x, v2.y, v2.z, v2.w};
    float q[12];
#pragma unroll
    for (int j = 0; j < 4; ++j) {
        const float px = p[3 * j + 0];
        const float py = p[3 * j + 1];
        const float pz = p[3 * j + 2];
        q[3 * j + 0] = r00 * px + r01 * py + r02 * pz;
        q[3 * j + 1] = r10 * px + r11 * py + r12 * pz;
        q[3 * j + 2] = r20 * px + r21 * py + r22 * pz;
    }

    float4* __restrict__ o = reinterpret_cast<float4*>(out + base);
    o[0] = make_float4(q[0], q[1], q[2], q[3]);
    o[1] = make_float4(q[4], q[5], q[6], q[7]);
    o[2] = make_float4(q[8], q[9], q[10], q[11]);
}

extern "C" void kernel_launch(void* const* d_in, const int* in_sizes, int n_in,
                              void* d_out, int out_size, void* d_ws, size_t ws_size,
                              hipStream_t stream) {
    const float* x     = (const float*)d_in[0];
    const float* theta = (const float*)d_in[1];
    float* out = (float*)d_out;

    const long total = (long)in_sizes[0];      // B*S*D floats
    const int B = in_sizes[1] / 3;             // 512
    const long per_b = total / B;              // 76800 floats
    const int blocks_per_b = (int)(per_b / ((long)BLOCK * FPT));  // 25
    const int grid = B * blocks_per_b;         // 12800

    rot3_kernel<<<grid, BLOCK, 0, stream>>>(x, theta, out, blocks_per_b, total);
}

// Round 2
// 53.863 us; speedup vs baseline: 1.1768x; 1.1768x over previous
//
#include <hip/hip_runtime.h>

#define BLOCK 256
#define TPT 4                                   // triples per thread
#define TRIPLES_PER_BLOCK (BLOCK * TPT)         // 1024
#define FLOATS_PER_BLOCK (TRIPLES_PER_BLOCK * 3) // 3072
#define VEC4_PER_BLOCK (FLOATS_PER_BLOCK / 4)   // 768 = 3 * BLOCK

__global__ __launch_bounds__(BLOCK)
void rot3_kernel(const float4* __restrict__ x4, const float* __restrict__ theta,
                 float4* __restrict__ out4, int blocks_per_b) {
    __shared__ float buf[FLOATS_PER_BLOCK];
    __shared__ float Rs[9];

    const int tid = threadIdx.x;
    const long vbase = (long)blockIdx.x * VEC4_PER_BLOCK;

    // Coalesced loads issued first: HBM latency hides under the sincos below.
    const float4 v0 = x4[vbase + tid];
    const float4 v1 = x4[vbase + tid + BLOCK];
    const float4 v2 = x4[vbase + tid + 2 * BLOCK];

    if (tid == 0) {
        const int b = blockIdx.x / blocks_per_b;
        // Indexing per reference: Rx uses th[1], Ry uses th[0], Rz uses th[2]
        const float t0 = theta[3 * b + 0];
        const float t1 = theta[3 * b + 1];
        const float t2 = theta[3 * b + 2];
        float sx, cx, sy, cy, sz, cz;
        sincosf(t1, &sx, &cx);
        sincosf(t0, &sy, &cy);
        sincosf(t2, &sz, &cz);
        // R = Rz * Ry * Rx (3x3 block; homogeneous part is identity)
        Rs[0] = cz * cy;
        Rs[1] = cz * sy * sx - sz * cx;
        Rs[2] = sz * sx + cz * sy * cx;
        Rs[3] = sz * cy;
        Rs[4] = cz * cx + sz * sy * sx;
        Rs[5] = sz * sy * cx - cz * sx;
        Rs[6] = -sy;
        Rs[7] = cy * sx;
        Rs[8] = cy * cx;
    }

    float4* bufv = reinterpret_cast<float4*>(buf);
    bufv[tid]             = v0;
    bufv[tid + BLOCK]     = v1;
    bufv[tid + 2 * BLOCK] = v2;
    __syncthreads();

    const float r00 = Rs[0], r01 = Rs[1], r02 = Rs[2];
    const float r10 = Rs[3], r11 = Rs[4], r12 = Rs[5];
    const float r20 = Rs[6], r21 = Rs[7], r22 = Rs[8];

    // Thread t rotates triples {t, t+256, t+512, t+768} in place.
    // LDS float index 3*(t + j*256) + c -> bank (3t + c) mod 32: conflict-free.
#pragma unroll
    for (int j = 0; j < TPT; ++j) {
        const int f = 3 * (tid + j * BLOCK);
        const float px = buf[f + 0];
        const float py = buf[f + 1];
        const float pz = buf[f + 2];
        buf[f + 0] = r00 * px + r01 * py + r02 * pz;
        buf[f + 1] = r10 * px + r11 * py + r12 * pz;
        buf[f + 2] = r20 * px + r21 * py + r22 * pz;
    }
    __syncthreads();

    // Coalesced stores.
    out4[vbase + tid]             = bufv[tid];
    out4[vbase + tid + BLOCK]     = bufv[tid + BLOCK];
    out4[vbase + tid + 2 * BLOCK] = bufv[tid + 2 * BLOCK];
}

extern "C" void kernel_launch(void* const* d_in, const int* in_sizes, int n_in,
                              void* d_out, int out_size, void* d_ws, size_t ws_size,
                              hipStream_t stream) {
    const float4* x4   = (const float4*)d_in[0];
    const float* theta = (const float*)d_in[1];
    float4* out4 = (float4*)d_out;

    const long total = (long)in_sizes[0];                 // B*S*D floats (39,321,600)
    const int B = in_sizes[1] / 3;                        // 512
    const int grid = (int)(total / FLOATS_PER_BLOCK);     // 12800, exact
    const int blocks_per_b = grid / B;                    // 25, exact

    rot3_kernel<<<grid, BLOCK, 0, stream>>>(x4, theta, out4, blocks_per_b);
}

// Round 4
// 50.306 us; speedup vs baseline: 1.2600x; 1.0707x over previous
//
#include <hip/hip_runtime.h>

#define BLOCK 256
#define TPT 4                                    // triples per thread
#define TRIPLES_PER_BLOCK (BLOCK * TPT)          // 1024
#define FLOATS_PER_BLOCK (TRIPLES_PER_BLOCK * 3) // 3072
#define VEC4_PER_BLOCK (FLOATS_PER_BLOCK / 4)    // 768 = 3 * BLOCK

typedef float f32x4 __attribute__((ext_vector_type(4)));

__global__ __launch_bounds__(BLOCK)
void rot3_kernel(const f32x4* __restrict__ x4, const float* __restrict__ theta,
                 f32x4* __restrict__ out4, int blocks_per_b) {
    __shared__ float buf[FLOATS_PER_BLOCK];
    __shared__ float Rs[9];

    const int tid = threadIdx.x;
    const long vbase = (long)blockIdx.x * VEC4_PER_BLOCK;

    // Coalesced loads issued first: HBM latency hides under the sincos below.
    // Plain loads (allocate in L2/L3): input is re-read every replay, keep it cached.
    const f32x4 v0 = x4[vbase + tid];
    const f32x4 v1 = x4[vbase + tid + BLOCK];
    const f32x4 v2 = x4[vbase + tid + 2 * BLOCK];

    if (tid == 0) {
        const int b = blockIdx.x / blocks_per_b;
        // Indexing per reference: Rx uses th[1], Ry uses th[0], Rz uses th[2]
        const float t0 = theta[3 * b + 0];
        const float t1 = theta[3 * b + 1];
        const float t2 = theta[3 * b + 2];
        float sx, cx, sy, cy, sz, cz;
        sincosf(t1, &sx, &cx);
        sincosf(t0, &sy, &cy);
        sincosf(t2, &sz, &cz);
        // R = Rz * Ry * Rx (3x3 block; homogeneous part is identity)
        Rs[0] = cz * cy;
        Rs[1] = cz * sy * sx - sz * cx;
        Rs[2] = sz * sx + cz * sy * cx;
        Rs[3] = sz * cy;
        Rs[4] = cz * cx + sz * sy * sx;
        Rs[5] = sz * sy * cx - cz * sx;
        Rs[6] = -sy;
        Rs[7] = cy * sx;
        Rs[8] = cy * cx;
    }

    f32x4* bufv = reinterpret_cast<f32x4*>(buf);
    bufv[tid]             = v0;
    bufv[tid + BLOCK]     = v1;
    bufv[tid + 2 * BLOCK] = v2;
    __syncthreads();

    const float r00 = Rs[0], r01 = Rs[1], r02 = Rs[2];
    const float r10 = Rs[3], r11 = Rs[4], r12 = Rs[5];
    const float r20 = Rs[6], r21 = Rs[7], r22 = Rs[8];

    // Thread t rotates triples {t, t+256, t+512, t+768} in place.
    // LDS float index 3*(t + j*256) + c -> bank (3t + c) mod 32: conflict-free.
#pragma unroll
    for (int j = 0; j < TPT; ++j) {
        const int f = 3 * (tid + j * BLOCK);
        const float px = buf[f + 0];
        const float py = buf[f + 1];
        const float pz = buf[f + 2];
        buf[f + 0] = r00 * px + r01 * py + r02 * pz;
        buf[f + 1] = r10 * px + r11 * py + r12 * pz;
        buf[f + 2] = r20 * px + r21 * py + r22 * pz;
    }
    __syncthreads();

    // Coalesced NON-TEMPORAL stores: output is never re-read by the kernel;
    // nt keeps it from evicting the (re-read every replay) input out of L3.
    __builtin_nontemporal_store(bufv[tid],             &out4[vbase + tid]);
    __builtin_nontemporal_store(bufv[tid + BLOCK],     &out4[vbase + tid + BLOCK]);
    __builtin_nontemporal_store(bufv[tid + 2 * BLOCK], &out4[vbase + tid + 2 * BLOCK]);
}

extern "C" void kernel_launch(void* const* d_in, const int* in_sizes, int n_in,
                              void* d_out, int out_size, void* d_ws, size_t ws_size,
                              hipStream_t stream) {
    const f32x4* x4    = (const f32x4*)d_in[0];
    const float* theta = (const float*)d_in[1];
    f32x4* out4 = (f32x4*)d_out;

    const long total = (long)in_sizes[0];                 // B*S*D floats (39,321,600)
    const int B = in_sizes[1] / 3;                        // 512
    const int grid = (int)(total / FLOATS_PER_BLOCK);     // 12800, exact
    const int blocks_per_b = grid / B;                    // 25, exact

    rot3_kernel<<<grid, BLOCK, 0, stream>>>(x4, theta, out4, blocks_per_b);
}